// Round 4
// baseline (238.613 us; speedup 1.0000x reference)
//
#include <hip/hip_runtime.h>

#define DIM 64
#define MTILE 128        // rows per block
#define NCHUNK 128       // codes per k-chunk
#define NCHUNKS 8        // 1024 / 128
#define THREADS 512
#define T_LEN 2048
#define PITCH 68         // 64 + 4 pad: keeps 16B alignment, spreads banks
#define RT 8             // rows per thread
#define CT 4             // codes per thread

// monotone order-preserving map float -> u32
__device__ __forceinline__ unsigned int fmap32(float s) {
    unsigned int b = __float_as_uint(s);
    return (b & 0x80000000u) ? ~b : (b | 0x80000000u);
}
__device__ __forceinline__ float funmap32(unsigned int m) {
    unsigned int b = (m & 0x80000000u) ? (m & 0x7fffffffu) : ~m;
    return __uint_as_float(b);
}

// numpy pairwise-sum (n=64 scalar blocked path) combine tree over 8 partials
__device__ __forceinline__ float np_combine8(const float* r) {
    return __fadd_rn(__fadd_rn(__fadd_rn(r[0], r[1]), __fadd_rn(r[2], r[3])),
                     __fadd_rn(__fadd_rn(r[4], r[5]), __fadd_rn(r[6], r[7])));
}

__global__ void vq_init_ws(double* ws) { ws[0] = 0.0; }

__global__ void vq_finalize_atomic(const double* __restrict__ ws,
                                   float* __restrict__ out_loss, int n_el) {
    out_loss[0] = (float)(1.25 * ws[0] / (double)n_el);
}

// sums 512 per-block partials (one block, 512 threads)
__global__ void vq_finalize_part(const double* __restrict__ ws,
                                 float* __restrict__ out_loss, int n_el) {
    __shared__ double red[8];
    double v = ws[threadIdx.x];
    #pragma unroll
    for (int off = 32; off > 0; off >>= 1) v += __shfl_down(v, off, 64);
    if ((threadIdx.x & 63) == 0) red[threadIdx.x >> 6] = v;
    __syncthreads();
    if (threadIdx.x == 0) {
        double s = 0.0;
        #pragma unroll
        for (int i = 0; i < 8; ++i) s += red[i];
        out_loss[0] = (float)(1.25 * s / (double)n_el);
    }
}

// Replicates numpy fp32 semantics bitwise:
//   D[n,k] = fl32( fl32(A_n + B_k) - 2*M[n,k] ),  M = sequential fp32 fma chain over i,
//   A_n, B_k = numpy pairwise (8-partial) fp32 sums.  argmin w/ first-index tie-break.
// 512 threads: tc = tid&31 (code group, CT=4 codes spaced 32),
//              tr = tid>>5 (row group, RT=8 rows spaced 16).
__global__ __launch_bounds__(THREADS, 4) void vq_main(
        const float* __restrict__ x,
        const float* __restrict__ cb,
        float* __restrict__ out_q,
        float* __restrict__ out_idx,
        double* __restrict__ wsd,
        int use_partials)
{
    __shared__ alignas(16) float xs[MTILE * PITCH];
    __shared__ alignas(16) float cs[NCHUNK * PITCH];
    __shared__ float  bnorm[1024];
    __shared__ float  anorm[MTILE];
    __shared__ int    kstar[MTILE];
    __shared__ double lossred[16];

    const int tid  = threadIdx.x;
    const int tc   = tid & 31;
    const int tr   = tid >> 5;
    const int lane = tid & 63;
    const int wv   = tid >> 6;   // wave in block (0..7)
    const int r0   = blockIdx.x * MTILE;

    // ---- stage x tile (row-major, padded); coalesced float4 ----
    const float4* x4 = (const float4*)x;
    const int srow = tid >> 4, sf4 = tid & 15;       // 32 rows per it-step
    #pragma unroll
    for (int it = 0; it < 4; ++it) {
        int row = it * 32 + srow;
        float4 v = x4[(size_t)(r0 + row) * 16 + sf4];
        *(float4*)&xs[row * PITCH + sf4 * 4] = v;
    }

    // ---- B_k for all 1024 codes (numpy register routine, bit-exact) ----
    #pragma unroll
    for (int j = 0; j < 2; ++j) {
        int k = tid * 2 + j;
        const float4* c4 = (const float4*)(cb + (size_t)k * DIM);
        float r8[8];
        {
            float4 a = c4[0], b = c4[1];
            r8[0] = __fmul_rn(a.x, a.x); r8[1] = __fmul_rn(a.y, a.y);
            r8[2] = __fmul_rn(a.z, a.z); r8[3] = __fmul_rn(a.w, a.w);
            r8[4] = __fmul_rn(b.x, b.x); r8[5] = __fmul_rn(b.y, b.y);
            r8[6] = __fmul_rn(b.z, b.z); r8[7] = __fmul_rn(b.w, b.w);
        }
        #pragma unroll
        for (int m = 1; m < 8; ++m) {
            float4 a = c4[2 * m], b = c4[2 * m + 1];
            r8[0] = __fadd_rn(r8[0], __fmul_rn(a.x, a.x));
            r8[1] = __fadd_rn(r8[1], __fmul_rn(a.y, a.y));
            r8[2] = __fadd_rn(r8[2], __fmul_rn(a.z, a.z));
            r8[3] = __fadd_rn(r8[3], __fmul_rn(a.w, a.w));
            r8[4] = __fadd_rn(r8[4], __fmul_rn(b.x, b.x));
            r8[5] = __fadd_rn(r8[5], __fmul_rn(b.y, b.y));
            r8[6] = __fadd_rn(r8[6], __fmul_rn(b.z, b.z));
            r8[7] = __fadd_rn(r8[7], __fmul_rn(b.w, b.w));
        }
        bnorm[k] = np_combine8(r8);
    }

    __syncthreads();  // xs ready for cross-thread anorm reads

    // ---- A_n for 128 rows (numpy shuffle routine, bit-identical) ----
    for (int j = 0; j < MTILE / 8; ++j) {   // 16 rows per wave
        int row = wv * (MTILE / 8) + j;
        float v  = xs[row * PITCH + lane];
        float pp = __fmul_rn(v, v);
        float r = __fadd_rn(pp, __shfl_down(pp, 8, 64));
        r = __fadd_rn(r, __shfl_down(pp, 16, 64));
        r = __fadd_rn(r, __shfl_down(pp, 24, 64));
        r = __fadd_rn(r, __shfl_down(pp, 32, 64));
        r = __fadd_rn(r, __shfl_down(pp, 40, 64));
        r = __fadd_rn(r, __shfl_down(pp, 48, 64));
        r = __fadd_rn(r, __shfl_down(pp, 56, 64));
        float rr[8];
        #pragma unroll
        for (int q = 0; q < 8; ++q) rr[q] = __shfl(r, q, 64);
        if (lane == 0) anorm[row] = np_combine8(rr);
    }

    unsigned long long rowmin[RT];
    #pragma unroll
    for (int r = 0; r < RT; ++r) rowmin[r] = ~0ULL;

    // ---- prefetch chunk 0 into registers ----
    float4 pref[4];
    #pragma unroll
    for (int it = 0; it < 4; ++it)
        pref[it] = ((const float4*)cb)[(size_t)(it * 32 + srow) * 16 + sf4];

    // ---- main k-chunk loop ----
    for (int ch = 0; ch < NCHUNKS; ++ch) {
        __syncthreads();  // prior chunk's cs readers done (ch0: fences anorm/bnorm too)
        #pragma unroll
        for (int it = 0; it < 4; ++it)
            *(float4*)&cs[(it * 32 + srow) * PITCH + sf4 * 4] = pref[it];
        if (ch + 1 < NCHUNKS) {
            const int kc2 = (ch + 1) * NCHUNK;
            #pragma unroll
            for (int it = 0; it < 4; ++it)
                pref[it] = ((const float4*)cb)[(size_t)(kc2 + it * 32 + srow) * 16 + sf4];
        }
        __syncthreads();
        const int kc = ch * NCHUNK;

        float acc[RT][CT];
        #pragma unroll
        for (int r = 0; r < RT; ++r)
            #pragma unroll
            for (int c = 0; c < CT; ++c) acc[r][c] = 0.0f;

        #pragma unroll 1
        for (int i4 = 0; i4 < DIM; i4 += 4) {
            float4 xv[RT], ev[CT];
            #pragma unroll
            for (int r = 0; r < RT; ++r)
                xv[r] = *(const float4*)&xs[(tr + 16 * r) * PITCH + i4];
            #pragma unroll
            for (int c = 0; c < CT; ++c)
                ev[c] = *(const float4*)&cs[(tc + 32 * c) * PITCH + i4];
            #pragma unroll
            for (int q = 0; q < 4; ++q) {   // q outer: i-sequential chain per acc
                #pragma unroll
                for (int r = 0; r < RT; ++r) {
                    float xq = ((const float*)&xv[r])[q];
                    #pragma unroll
                    for (int c = 0; c < CT; ++c) {
                        float eq = ((const float*)&ev[c])[q];
                        acc[r][c] = __fmaf_rn(xq, eq, acc[r][c]);
                    }
                }
            }
        }

        // d = fl(fl(A+B) - 2*acc); merge packed key into running row minima
        #pragma unroll
        for (int c = 0; c < CT; ++c) {
            const int kk = kc + tc + 32 * c;
            const float b2 = bnorm[kk];
            #pragma unroll
            for (int r = 0; r < RT; ++r) {
                float t1 = __fadd_rn(anorm[tr + 16 * r], b2);
                float d  = __fsub_rn(t1, __fmul_rn(2.0f, acc[r][c]));
                unsigned long long key =
                    ((unsigned long long)fmap32(d) << 12) | (unsigned long long)kk;
                rowmin[r] = (key < rowmin[r]) ? key : rowmin[r];
            }
        }
    }

    // ---- reduce across 32 code-groups (half-wave sharing tr) ----
    #pragma unroll
    for (int r = 0; r < RT; ++r) {
        unsigned long long kmin = rowmin[r];
        #pragma unroll
        for (int off = 1; off < 32; off <<= 1) {
            unsigned long long o = __shfl_xor(kmin, off, 64);
            kmin = (o < kmin) ? o : kmin;
        }
        rowmin[r] = kmin;
    }
    if (tc == 0) {
        double loss_part = 0.0;
        #pragma unroll
        for (int r = 0; r < RT; ++r) {
            kstar[tr + 16 * r] = (int)(rowmin[r] & 0xFFFULL);
            loss_part += (double)funmap32((unsigned int)(rowmin[r] >> 12));
        }
        lossred[tr] = loss_part;
    }
    __syncthreads();

    // ---- epilogue ----
    if (tid < MTILE) out_idx[r0 + tid] = (float)kstar[tid];

    const int bb = r0 / T_LEN;
    const int t0 = r0 % T_LEN;
    #pragma unroll
    for (int it = 0; it < (MTILE * DIM) / THREADS; ++it) {  // 16
        int idx = it * THREADS + tid;
        int d = idx >> 7, t = idx & 127;
        out_q[((size_t)bb * DIM + d) * T_LEN + (t0 + t)] = cb[(size_t)kstar[t] * DIM + d];
    }
    if (tid == 0) {
        double s = 0.0;
        #pragma unroll
        for (int i = 0; i < 16; ++i) s += lossred[i];
        if (use_partials) wsd[blockIdx.x] = s;
        else atomicAdd(wsd, s);
    }
}

extern "C" void kernel_launch(void* const* d_in, const int* in_sizes, int n_in,
                              void* d_out, int out_size, void* d_ws, size_t ws_size,
                              hipStream_t stream) {
    const float* x  = (const float*)d_in[0];
    const float* cb = (const float*)d_in[1];
    float* out = (float*)d_out;

    const int n_x = in_sizes[0];           // 4194304
    const int n_rows = n_x / DIM;          // 65536
    const int n_blocks = n_rows / MTILE;   // 512

    float* out_q    = out;                    // [B, D, T]
    float* out_loss = out + (size_t)n_x;      // scalar
    float* out_idx  = out + (size_t)n_x + 1;  // [B, T] as float
    double* wsd = (double*)d_ws;

    const int use_partials = (ws_size >= (size_t)n_blocks * sizeof(double)) ? 1 : 0;
    if (!use_partials) vq_init_ws<<<1, 1, 0, stream>>>(wsd);
    vq_main<<<n_blocks, THREADS, 0, stream>>>(x, cb, out_q, out_idx, wsd, use_partials);
    if (use_partials) vq_finalize_part<<<1, THREADS, 0, stream>>>(wsd, out_loss, n_x);
    else vq_finalize_atomic<<<1, 1, 0, stream>>>(wsd, out_loss, n_x);
}